// Round 11
// baseline (86.682 us; speedup 1.0000x reference)
//
#include <hip/hip_runtime.h>
#include <hip/hip_bf16.h>
#include <cstdint>

#define B_ 4096
#define D_ 256
#define M_ 60
#define NT_ 32          // 128-tiles per dimension
#define NBLK 528        // NT_*(NT_+1)/2 upper-triangle tiles
#define BM 128
#define BK 64           // bf16 elements per K-step (128 bytes/row)

typedef unsigned long long u64;
typedef short bf16x8 __attribute__((ext_vector_type(8)));   // 8 bf16 = 4 VGPRs
typedef float f32x4 __attribute__((ext_vector_type(4)));

__device__ __forceinline__ unsigned short f2bf(float x) {
    __hip_bfloat16 b = __float2bfloat16(x);
    return __builtin_bit_cast(unsigned short, b);
}

// ---------- prep: bf16 cast of raw rep, inv-norm*sqrt(10), code masks, zero done ----------
__global__ __launch_bounds__(256) void prep_kernel(
    const float* __restrict__ rep, const int* __restrict__ codes,
    unsigned short* __restrict__ nb, float* __restrict__ invs,
    u64* __restrict__ lo, u64* __restrict__ hi, int* __restrict__ cnt,
    u64* __restrict__ done) {
    const int w = threadIdx.x >> 6;
    const int lane = threadIdx.x & 63;
    const int row = blockIdx.x * 4 + w;

    float4 v = ((const float4*)(rep + (size_t)row * D_))[lane];
    float ss = v.x * v.x + v.y * v.y + v.z * v.z + v.w * v.w;
#pragma unroll
    for (int off = 32; off > 0; off >>= 1) ss += __shfl_down(ss, off);
    ss = __shfl(ss, 0);

    // store RAW bf16 (normalization folded into epilogue scale)
    ushort4 o;
    o.x = f2bf(v.x); o.y = f2bf(v.y); o.z = f2bf(v.z); o.w = f2bf(v.w);
    ((ushort4*)(nb + (size_t)row * D_))[lane] = o;

    // code membership mask via wave-OR reduction
    u64 l = 0, h = 0;
    if (lane < M_) {
        int c = codes[row * M_ + lane];
        if (c < 64) l = 1ull << c;
        else        h = 1ull << (c - 64);
    }
#pragma unroll
    for (int off = 32; off > 0; off >>= 1) {
        l |= __shfl_down(l, off);
        h |= __shfl_down(h, off);
    }
    if (lane == 0) {
        invs[row] = (1.0f / sqrtf(ss)) * 3.16227766016838f;  // inv_norm * sqrt(1/T)
        lo[row] = l; hi[row] = h;
        cnt[row] = __popcll(l) + __popcll(h);
    }
    if (blockIdx.x == 0 && threadIdx.x == 0) *done = 0ull;
}

// ---------- fused: 512-thr (8-wave) MFMA sim-GEMM + jaccard + partials + last-block finalize ----------
// Wave w owns a 64x32 quadrant: wr=w>>2 selects row half, wc=w&3 selects col quarter.
__global__ __launch_bounds__(512) void fused_kernel(
    const unsigned short* __restrict__ Nb, const float* __restrict__ invs,
    const u64* __restrict__ lo, const u64* __restrict__ hi, const int* __restrict__ cnt,
    double* __restrict__ partials /* NBLK x 8 doubles (64B stride) */,
    u64* __restrict__ done, float* __restrict__ out) {
    // 16 KB per operand tile: 128 rows x 64 bf16 (128 B/row), XOR-swizzled 16B chunks
    __shared__ __attribute__((aligned(16))) char AsB[BM * BK * 2];
    __shared__ __attribute__((aligned(16))) char BsB[BM * BK * 2];
    __shared__ float redT[8], redPe[8], redPs[8];
    __shared__ int redC[8];
    __shared__ int lastSh;

    const int tid = threadIdx.x;
    const int lane = tid & 63;
    const int w = tid >> 6;          // 0..7
    const int wr = w >> 2, wc = w & 3;
    const int quad = lane >> 4;
    const int l15 = lane & 15;
    const int l7 = lane & 7;

    // block -> (bi, bj) with bj >= bi
    int q = blockIdx.x, bi = 0;
    while (q >= NT_ - bi) { q -= NT_ - bi; bi++; }
    const int bj = bi + q;
    const int rowA = bi * BM, rowB = bj * BM;

    // hoist column-side epilogue data (independent of GEMM; latency fully hidden)
    int colg[2]; u64 jl[2], jh[2]; int jc[2]; float ib[2];
#pragma unroll
    for (int nt = 0; nt < 2; nt++) {
        int cg = rowB + wc * 32 + nt * 16 + l15;
        colg[nt] = cg; jl[nt] = lo[cg]; jh[nt] = hi[cg]; jc[nt] = cnt[cg];
        ib[nt] = invs[cg];
    }

    f32x4 accf[4][2] = {};

    for (int k0 = 0; k0 < D_; k0 += BK) {
        __syncthreads();
        // stage A and B tiles via async global->LDS, 16B per lane, 2 shots x 8 waves
        // physical chunk P = region*64 + lane; row = P>>3, pc = P&7, logical chunk c = pc ^ (row&7)
#pragma unroll
        for (int it = 0; it < 2; it++) {
            int region = it * 8 + w;          // 0..15
            int P = region * 64 + lane;       // 0..1023
            int row = P >> 3;
            int c = (P & 7) ^ (row & 7);
            const unsigned short* gA = Nb + (size_t)(rowA + row) * D_ + k0 + c * 8;
            const unsigned short* gB = Nb + (size_t)(rowB + row) * D_ + k0 + c * 8;
            __builtin_amdgcn_global_load_lds(
                (const __attribute__((address_space(1))) void*)gA,
                (__attribute__((address_space(3))) void*)(AsB + region * 1024), 16, 0, 0);
            __builtin_amdgcn_global_load_lds(
                (const __attribute__((address_space(1))) void*)gB,
                (__attribute__((address_space(3))) void*)(BsB + region * 1024), 16, 0, 0);
        }
        __syncthreads();
        // compute: 2 mfma-K groups x 8 mfma (wave quadrant = 64 rows x 32 cols)
#pragma unroll
        for (int kk = 0; kk < 2; kk++) {
            int pc = (kk * 4 + quad) ^ l7;   // swizzled chunk (rows == l15 mod 8 -> ^l7)
            bf16x8 a[4], b[2];
#pragma unroll
            for (int t = 0; t < 4; t++) {
                int rA = wr * 64 + t * 16 + l15;
                a[t] = *(const bf16x8*)(AsB + rA * 128 + pc * 16);
            }
#pragma unroll
            for (int u = 0; u < 2; u++) {
                int rB = wc * 32 + u * 16 + l15;
                b[u] = *(const bf16x8*)(BsB + rB * 128 + pc * 16);
            }
#pragma unroll
            for (int i = 0; i < 4; i++)
#pragma unroll
                for (int j = 0; j < 2; j++)
                    accf[i][j] = __builtin_amdgcn_mfma_f32_16x16x32_bf16(a[i], b[j], accf[i][j], 0, 0, 0);
        }
    }

    // ---------- epilogue ----------
    // C/D layout (16x16): col = lane&15, row = quad*4 + reg
    float t_sum = 0.0f, p_exp = 0.0f, p_s = 0.0f;
    int p_cnt = 0;
#pragma unroll
    for (int mt = 0; mt < 4; mt++) {
        int rbase = rowA + wr * 64 + mt * 16 + quad * 4;
        u64 al[4], ah[4]; int ac[4]; float ia[4];
#pragma unroll
        for (int r = 0; r < 4; r++) {
            al[r] = lo[rbase + r]; ah[r] = hi[rbase + r];
            ac[r] = cnt[rbase + r]; ia[r] = invs[rbase + r];
        }
#pragma unroll
        for (int nt = 0; nt < 2; nt++) {
#pragma unroll
            for (int r = 0; r < 4; r++) {
                float s = accf[mt][nt][r] * ia[r] * ib[nt];   // dot * inv_i*inv_j*10
                float es = __expf(s);
                t_sum += es;
                int inter = __popcll(al[r] & jl[nt]) + __popcll(ah[r] & jh[nt]);
                int uni = ac[r] + jc[nt] - inter;
                if ((10 * inter > 3 * uni) && (rbase + r != colg[nt])) {
                    p_exp += es; p_s += s; p_cnt++;
                }
            }
        }
    }

    // per-wave reduction, LDS combine, plain stores + ONE done-increment per block
#pragma unroll
    for (int off = 32; off > 0; off >>= 1) {
        t_sum += __shfl_down(t_sum, off);
        p_exp += __shfl_down(p_exp, off);
        p_s   += __shfl_down(p_s, off);
        p_cnt += __shfl_down(p_cnt, off);
    }
    if (lane == 0) { redT[w] = t_sum; redPe[w] = p_exp; redPs[w] = p_s; redC[w] = p_cnt; }
    __syncthreads();
    if (tid == 0) {
        double T = 0, Pe = 0, Ps = 0;
        long long C = 0;
        for (int i = 0; i < 8; i++) {
            T += (double)redT[i]; Pe += (double)redPe[i];
            Ps += (double)redPs[i]; C += redC[i];
        }
        double scale = (bi == bj) ? 1.0 : 2.0;   // symmetry: off-diagonal counts twice
        double* dst = partials + (size_t)blockIdx.x * 8;  // own 64B line, plain stores
        dst[0] = T * scale;
        dst[1] = Pe * scale;
        dst[2] = Ps * scale;
        dst[3] = (double)C * scale;
        __threadfence();                     // partials visible before done increment
        u64 old = atomicAdd(done, 1ull);     // single same-address atomic per block
        lastSh = (old == (u64)(NBLK - 1)) ? 1 : 0;
    }
    __syncthreads();

    // ---------- last-block finalize: device-scope atomic readback (XCD-safe) ----------
    if (lastSh) {
        double T = 0, Pe = 0, Ps = 0, C = 0;
        for (int i = tid; i < NBLK; i += 512) {
            u64* src = (u64*)(partials + (size_t)i * 8);
            T  += __longlong_as_double((long long)atomicAdd(&src[0], 0ull));
            Pe += __longlong_as_double((long long)atomicAdd(&src[1], 0ull));
            Ps += __longlong_as_double((long long)atomicAdd(&src[2], 0ull));
            C  += __longlong_as_double((long long)atomicAdd(&src[3], 0ull));
        }
#pragma unroll
        for (int off = 32; off > 0; off >>= 1) {
            T += __shfl_down(T, off);
            Pe += __shfl_down(Pe, off);
            Ps += __shfl_down(Ps, off);
            C += __shfl_down(C, off);
        }
        __shared__ double fT[8], fPe[8], fPs[8], fC[8];
        if (lane == 0) { fT[w] = T; fPe[w] = Pe; fPs[w] = Ps; fC[w] = C; }
        __syncthreads();
        if (tid == 0) {
            double Tt = 0, Pet = 0, Pst = 0, n = 0;
            for (int i = 0; i < 8; i++) { Tt += fT[i]; Pet += fPe[i]; Pst += fPs[i]; n += fC[i]; }
            double neg = Tt - Pet;   // negatives incl. diagonal
            double loss = (n > 0.0) ? log(neg) + (Pet / neg - Pst) / n : 0.0;
            out[0] = (float)loss;
        }
    }
}

extern "C" void kernel_launch(void* const* d_in, const int* in_sizes, int n_in,
                              void* d_out, int out_size, void* d_ws, size_t ws_size,
                              hipStream_t stream) {
    const float* rep = (const float*)d_in[0];
    const int* codes = (const int*)d_in[1];
    // d_in[2] = labels, unused by the reference computation

    // workspace layout
    unsigned short* nb = (unsigned short*)d_ws;                // 2 MiB raw bf16
    char* p = (char*)d_ws + (size_t)B_ * D_ * 2;
    float* invs = (float*)p;                                   // 16 KiB
    u64* lo = (u64*)(invs + B_);                               // 32 KiB
    u64* hi = lo + B_;                                         // 32 KiB
    int* cnt = (int*)(hi + B_);                                // 16 KiB
    double* partials = (double*)(cnt + B_);                    // 528 x 8 doubles = 33 KiB
    u64* done = (u64*)(partials + (size_t)NBLK * 8);

    float* out = (float*)d_out;

    prep_kernel<<<B_ / 4, 256, 0, stream>>>(rep, codes, nb, invs, lo, hi, cnt, done);
    fused_kernel<<<NBLK, 512, 0, stream>>>(nb, invs, lo, hi, cnt, partials, done, out);
}

// Round 12
// 82.814 us; speedup vs baseline: 1.0467x; 1.0467x over previous
//
#include <hip/hip_runtime.h>
#include <hip/hip_bf16.h>
#include <cstdint>

#define B_ 4096
#define D_ 256
#define M_ 60
#define NT_ 32          // 128-tiles per dimension
#define NBLK 528        // NT_*(NT_+1)/2 upper-triangle tiles
#define BM 128
#define BK 64           // bf16 elements per K-step (128 bytes/row)

typedef unsigned long long u64;
typedef short bf16x8 __attribute__((ext_vector_type(8)));   // 8 bf16 = 4 VGPRs
typedef float f32x4 __attribute__((ext_vector_type(4)));

__device__ __forceinline__ unsigned short f2bf(float x) {
    __hip_bfloat16 b = __float2bfloat16(x);
    return __builtin_bit_cast(unsigned short, b);
}

// ---------- prep: bf16 cast of raw rep, inv-norm*sqrt(10), code masks (coalesced, once) ----------
__global__ __launch_bounds__(256) void prep_kernel(
    const float* __restrict__ rep, const int* __restrict__ codes,
    unsigned short* __restrict__ nb, float* __restrict__ invs,
    u64* __restrict__ lo, u64* __restrict__ hi, int* __restrict__ cnt) {
    const int w = threadIdx.x >> 6;
    const int lane = threadIdx.x & 63;
    const int row = blockIdx.x * 4 + w;

    float4 v = ((const float4*)(rep + (size_t)row * D_))[lane];
    float ss = v.x * v.x + v.y * v.y + v.z * v.z + v.w * v.w;
#pragma unroll
    for (int off = 32; off > 0; off >>= 1) ss += __shfl_down(ss, off);
    ss = __shfl(ss, 0);

    // store RAW bf16 (normalization folded into epilogue scale)
    ushort4 o;
    o.x = f2bf(v.x); o.y = f2bf(v.y); o.z = f2bf(v.z); o.w = f2bf(v.w);
    ((ushort4*)(nb + (size_t)row * D_))[lane] = o;

    // code membership mask via wave-OR reduction
    u64 l = 0, h = 0;
    if (lane < M_) {
        int c = codes[row * M_ + lane];
        if (c < 64) l = 1ull << c;
        else        h = 1ull << (c - 64);
    }
#pragma unroll
    for (int off = 32; off > 0; off >>= 1) {
        l |= __shfl_down(l, off);
        h |= __shfl_down(h, off);
    }
    if (lane == 0) {
        invs[row] = (1.0f / sqrtf(ss)) * 3.16227766016838f;  // inv_norm * sqrt(1/T)
        lo[row] = l; hi[row] = h;
        cnt[row] = __popcll(l) + __popcll(h);
    }
}

// ---------- fused: 512-thread (8-wave) MFMA sim-GEMM + jaccard + partial STORE ----------
// Wave w owns a 64x32 quadrant: wr=w>>2 selects row half, wc=w&3 selects col quarter.
__global__ __launch_bounds__(512) void fused_kernel(
    const unsigned short* __restrict__ Nb, const float* __restrict__ invs,
    const u64* __restrict__ lo, const u64* __restrict__ hi, const int* __restrict__ cnt,
    double* __restrict__ partials /* NBLK x 8 doubles (64B stride) */) {
    // 16 KB per operand tile: 128 rows x 64 bf16 (128 B/row), XOR-swizzled 16B chunks
    __shared__ __attribute__((aligned(16))) char AsB[BM * BK * 2];
    __shared__ __attribute__((aligned(16))) char BsB[BM * BK * 2];
    __shared__ float redT[8], redPe[8], redPs[8];
    __shared__ int redC[8];

    const int tid = threadIdx.x;
    const int lane = tid & 63;
    const int w = tid >> 6;          // 0..7
    const int wr = w >> 2, wc = w & 3;
    const int quad = lane >> 4;
    const int l15 = lane & 15;
    const int l7 = lane & 7;

    // block -> (bi, bj) with bj >= bi
    int q = blockIdx.x, bi = 0;
    while (q >= NT_ - bi) { q -= NT_ - bi; bi++; }
    const int bj = bi + q;
    const int rowA = bi * BM, rowB = bj * BM;

    f32x4 accf[4][2] = {};

    for (int k0 = 0; k0 < D_; k0 += BK) {
        __syncthreads();
        // stage A and B tiles via async global->LDS, 16B per lane, 2 shots x 8 waves
        // physical chunk P = region*64 + lane; row = P>>3, pc = P&7, logical chunk c = pc ^ (row&7)
#pragma unroll
        for (int it = 0; it < 2; it++) {
            int region = it * 8 + w;          // 0..15
            int P = region * 64 + lane;       // 0..1023
            int row = P >> 3;
            int c = (P & 7) ^ (row & 7);
            const unsigned short* gA = Nb + (size_t)(rowA + row) * D_ + k0 + c * 8;
            const unsigned short* gB = Nb + (size_t)(rowB + row) * D_ + k0 + c * 8;
            __builtin_amdgcn_global_load_lds(
                (const __attribute__((address_space(1))) void*)gA,
                (__attribute__((address_space(3))) void*)(AsB + region * 1024), 16, 0, 0);
            __builtin_amdgcn_global_load_lds(
                (const __attribute__((address_space(1))) void*)gB,
                (__attribute__((address_space(3))) void*)(BsB + region * 1024), 16, 0, 0);
        }
        __syncthreads();
        // compute: 2 mfma-K groups x 8 mfma (wave quadrant = 64 rows x 32 cols)
#pragma unroll
        for (int kk = 0; kk < 2; kk++) {
            int pc = (kk * 4 + quad) ^ l7;   // swizzled chunk (rows are == l15 mod 8 -> ^l7)
            bf16x8 a[4], b[2];
#pragma unroll
            for (int t = 0; t < 4; t++) {
                int rA = wr * 64 + t * 16 + l15;
                a[t] = *(const bf16x8*)(AsB + rA * 128 + pc * 16);
            }
#pragma unroll
            for (int u = 0; u < 2; u++) {
                int rB = wc * 32 + u * 16 + l15;
                b[u] = *(const bf16x8*)(BsB + rB * 128 + pc * 16);
            }
#pragma unroll
            for (int i = 0; i < 4; i++)
#pragma unroll
                for (int j = 0; j < 2; j++)
                    accf[i][j] = __builtin_amdgcn_mfma_f32_16x16x32_bf16(a[i], b[j], accf[i][j], 0, 0, 0);
        }
    }

    // ---------- epilogue ----------
    // C/D layout (16x16): col = lane&15, row = quad*4 + reg
    int colg[2]; u64 jl[2], jh[2]; int jc[2]; float ib[2];
#pragma unroll
    for (int nt = 0; nt < 2; nt++) {
        int cg = rowB + wc * 32 + nt * 16 + l15;
        colg[nt] = cg; jl[nt] = lo[cg]; jh[nt] = hi[cg]; jc[nt] = cnt[cg];
        ib[nt] = invs[cg];
    }

    float t_sum = 0.0f, p_exp = 0.0f, p_s = 0.0f;
    int p_cnt = 0;
#pragma unroll
    for (int mt = 0; mt < 4; mt++) {
        int rbase = rowA + wr * 64 + mt * 16 + quad * 4;
        u64 al[4], ah[4]; int ac[4]; float ia[4];
#pragma unroll
        for (int r = 0; r < 4; r++) {
            al[r] = lo[rbase + r]; ah[r] = hi[rbase + r];
            ac[r] = cnt[rbase + r]; ia[r] = invs[rbase + r];
        }
#pragma unroll
        for (int nt = 0; nt < 2; nt++) {
#pragma unroll
            for (int r = 0; r < 4; r++) {
                float s = accf[mt][nt][r] * ia[r] * ib[nt];   // dot * inv_i*inv_j*10
                float es = __expf(s);
                t_sum += es;
                int inter = __popcll(al[r] & jl[nt]) + __popcll(ah[r] & jh[nt]);
                int uni = ac[r] + jc[nt] - inter;
                if ((10 * inter > 3 * uni) && (rbase + r != colg[nt])) {
                    p_exp += es; p_s += s; p_cnt++;
                }
            }
        }
    }

    // per-wave reduction, LDS combine, ONE uncontended store per block
#pragma unroll
    for (int off = 32; off > 0; off >>= 1) {
        t_sum += __shfl_down(t_sum, off);
        p_exp += __shfl_down(p_exp, off);
        p_s   += __shfl_down(p_s, off);
        p_cnt += __shfl_down(p_cnt, off);
    }
    if (lane == 0) { redT[w] = t_sum; redPe[w] = p_exp; redPs[w] = p_s; redC[w] = p_cnt; }
    __syncthreads();
    if (tid == 0) {
        double T = 0, Pe = 0, Ps = 0;
        long long C = 0;
        for (int i = 0; i < 8; i++) {
            T += (double)redT[i]; Pe += (double)redPe[i];
            Ps += (double)redPs[i]; C += redC[i];
        }
        double scale = (bi == bj) ? 1.0 : 2.0;   // symmetry: off-diagonal counts twice
        double* dst = partials + (size_t)blockIdx.x * 8;
        dst[0] = T * scale;
        dst[1] = Pe * scale;
        dst[2] = Ps * scale;
        dst[3] = (double)C * scale;
    }
}

// ---------- finalize: reduce 528 partials, compute loss ----------
__global__ __launch_bounds__(256) void finalize_kernel(
    const double* __restrict__ partials, float* __restrict__ out) {
    const int tid = threadIdx.x;
    const int lane = tid & 63;
    const int w = tid >> 6;
    double T = 0, Pe = 0, Ps = 0, C = 0;
    for (int i = tid; i < NBLK; i += 256) {
        const double* src = partials + (size_t)i * 8;
        T += src[0]; Pe += src[1]; Ps += src[2]; C += src[3];
    }
#pragma unroll
    for (int off = 32; off > 0; off >>= 1) {
        T += __shfl_down(T, off);
        Pe += __shfl_down(Pe, off);
        Ps += __shfl_down(Ps, off);
        C += __shfl_down(C, off);
    }
    __shared__ double redT[4], redPe[4], redPs[4], redC[4];
    if (lane == 0) { redT[w] = T; redPe[w] = Pe; redPs[w] = Ps; redC[w] = C; }
    __syncthreads();
    if (tid == 0) {
        double Tt = 0, Pet = 0, Pst = 0, n = 0;
        for (int i = 0; i < 4; i++) { Tt += redT[i]; Pet += redPe[i]; Pst += redPs[i]; n += redC[i]; }
        double neg = Tt - Pet;   // negatives incl. diagonal
        double loss = (n > 0.0) ? log(neg) + (Pet / neg - Pst) / n : 0.0;
        out[0] = (float)loss;
    }
}

extern "C" void kernel_launch(void* const* d_in, const int* in_sizes, int n_in,
                              void* d_out, int out_size, void* d_ws, size_t ws_size,
                              hipStream_t stream) {
    const float* rep = (const float*)d_in[0];
    const int* codes = (const int*)d_in[1];
    // d_in[2] = labels, unused by the reference computation

    // workspace layout
    unsigned short* nb = (unsigned short*)d_ws;                // 2 MiB raw bf16
    char* p = (char*)d_ws + (size_t)B_ * D_ * 2;
    float* invs = (float*)p;                                   // 16 KiB
    u64* lo = (u64*)(invs + B_);                               // 32 KiB
    u64* hi = lo + B_;                                         // 32 KiB
    int* cnt = (int*)(hi + B_);                                // 16 KiB
    double* partials = (double*)(cnt + B_);                    // 528 x 8 doubles = 33 KiB

    float* out = (float*)d_out;

    prep_kernel<<<B_ / 4, 256, 0, stream>>>(rep, codes, nb, invs, lo, hi, cnt);
    fused_kernel<<<NBLK, 512, 0, stream>>>(nb, invs, lo, hi, cnt, partials);
    finalize_kernel<<<1, 256, 0, stream>>>(partials, out);
}

// Round 13
// 80.925 us; speedup vs baseline: 1.0711x; 1.0233x over previous
//
#include <hip/hip_runtime.h>
#include <hip/hip_bf16.h>
#include <cstdint>

#define B_ 4096
#define D_ 256
#define M_ 60
#define NT_ 64          // 64-tiles per dimension
#define NBLK 2080       // NT_*(NT_+1)/2 upper-triangle tiles
#define BM 64
#define BK 64           // bf16 elements per K-step (128 bytes/row)

typedef unsigned long long u64;
typedef short bf16x8 __attribute__((ext_vector_type(8)));   // 8 bf16 = 4 VGPRs
typedef float f32x4 __attribute__((ext_vector_type(4)));

__device__ __forceinline__ unsigned short f2bf(float x) {
    __hip_bfloat16 b = __float2bfloat16(x);
    return __builtin_bit_cast(unsigned short, b);
}

// ---------- prep: bf16 cast of raw rep, inv-norm*sqrt(10), code masks (coalesced, once) ----------
__global__ __launch_bounds__(256) void prep_kernel(
    const float* __restrict__ rep, const int* __restrict__ codes,
    unsigned short* __restrict__ nb, float* __restrict__ invs,
    u64* __restrict__ lo, u64* __restrict__ hi, int* __restrict__ cnt) {
    const int w = threadIdx.x >> 6;
    const int lane = threadIdx.x & 63;
    const int row = blockIdx.x * 4 + w;

    float4 v = ((const float4*)(rep + (size_t)row * D_))[lane];
    float ss = v.x * v.x + v.y * v.y + v.z * v.z + v.w * v.w;
#pragma unroll
    for (int off = 32; off > 0; off >>= 1) ss += __shfl_down(ss, off);
    ss = __shfl(ss, 0);

    // store RAW bf16 (normalization folded into epilogue scale)
    ushort4 o;
    o.x = f2bf(v.x); o.y = f2bf(v.y); o.z = f2bf(v.z); o.w = f2bf(v.w);
    ((ushort4*)(nb + (size_t)row * D_))[lane] = o;

    // code membership mask via wave-OR reduction
    u64 l = 0, h = 0;
    if (lane < M_) {
        int c = codes[row * M_ + lane];
        if (c < 64) l = 1ull << c;
        else        h = 1ull << (c - 64);
    }
#pragma unroll
    for (int off = 32; off > 0; off >>= 1) {
        l |= __shfl_down(l, off);
        h |= __shfl_down(h, off);
    }
    if (lane == 0) {
        invs[row] = (1.0f / sqrtf(ss)) * 3.16227766016838f;  // inv_norm * sqrt(1/T)
        lo[row] = l; hi[row] = h;
        cnt[row] = __popcll(l) + __popcll(h);
    }
}

// ---------- fused: 64x64 tiles, 2080 blocks (8.1 blocks/CU), 4 waves, store partials ----------
// Wave w owns a 32x32 quadrant: wr=w>>1 row half, wc=w&1 col half.
__global__ __launch_bounds__(256) void fused_kernel(
    const unsigned short* __restrict__ Nb, const float* __restrict__ invs,
    const u64* __restrict__ lo, const u64* __restrict__ hi, const int* __restrict__ cnt,
    double* __restrict__ partials /* NBLK x 8 doubles (64B stride) */) {
    // 8 KB per operand tile: 64 rows x 64 bf16 (128 B/row), XOR-swizzled 16B chunks
    __shared__ __attribute__((aligned(16))) char AsB[BM * BK * 2];
    __shared__ __attribute__((aligned(16))) char BsB[BM * BK * 2];
    __shared__ float redT[4], redPe[4], redPs[4];
    __shared__ int redC[4];

    const int tid = threadIdx.x;
    const int lane = tid & 63;
    const int w = tid >> 6;          // 0..3
    const int wr = w >> 1, wc = w & 1;
    const int quad = lane >> 4;
    const int l15 = lane & 15;
    const int l7 = lane & 7;

    // block -> (bi, bj) with bj >= bi
    int q = blockIdx.x, bi = 0;
    while (q >= NT_ - bi) { q -= NT_ - bi; bi++; }
    const int bj = bi + q;
    const int rowA = bi * BM, rowB = bj * BM;

    // hoist column-side epilogue data
    int colg[2]; u64 jl[2], jh[2]; int jc[2]; float ib[2];
#pragma unroll
    for (int nt = 0; nt < 2; nt++) {
        int cg = rowB + wc * 32 + nt * 16 + l15;
        colg[nt] = cg; jl[nt] = lo[cg]; jh[nt] = hi[cg]; jc[nt] = cnt[cg];
        ib[nt] = invs[cg];
    }

    f32x4 accf[2][2] = {};

    for (int k0 = 0; k0 < D_; k0 += BK) {
        __syncthreads();
        // stage A and B tiles (8 KB each = 8 regions x 1024 B), 2 shots x 4 waves per operand
        // physical chunk P = region*64 + lane (0..511); row = P>>3, pc = P&7, c = pc ^ (row&7)
#pragma unroll
        for (int it = 0; it < 2; it++) {
            int region = it * 4 + w;          // 0..7
            int P = region * 64 + lane;       // 0..511
            int row = P >> 3;
            int c = (P & 7) ^ (row & 7);
            const unsigned short* gA = Nb + (size_t)(rowA + row) * D_ + k0 + c * 8;
            const unsigned short* gB = Nb + (size_t)(rowB + row) * D_ + k0 + c * 8;
            __builtin_amdgcn_global_load_lds(
                (const __attribute__((address_space(1))) void*)gA,
                (__attribute__((address_space(3))) void*)(AsB + region * 1024), 16, 0, 0);
            __builtin_amdgcn_global_load_lds(
                (const __attribute__((address_space(1))) void*)gB,
                (__attribute__((address_space(3))) void*)(BsB + region * 1024), 16, 0, 0);
        }
        __syncthreads();
        // compute: 2 mfma-K groups x 4 mfma (wave quadrant = 32 rows x 32 cols)
#pragma unroll
        for (int kk = 0; kk < 2; kk++) {
            int pc = (kk * 4 + quad) ^ l7;   // swizzled chunk (rows == l15 mod 8 -> ^l7)
            bf16x8 a[2], b[2];
#pragma unroll
            for (int t = 0; t < 2; t++) {
                int rA = wr * 32 + t * 16 + l15;
                a[t] = *(const bf16x8*)(AsB + rA * 128 + pc * 16);
                int rB = wc * 32 + t * 16 + l15;
                b[t] = *(const bf16x8*)(BsB + rB * 128 + pc * 16);
            }
#pragma unroll
            for (int i = 0; i < 2; i++)
#pragma unroll
                for (int j = 0; j < 2; j++)
                    accf[i][j] = __builtin_amdgcn_mfma_f32_16x16x32_bf16(a[i], b[j], accf[i][j], 0, 0, 0);
        }
    }

    // ---------- epilogue ----------
    // C/D layout (16x16): col = lane&15, row = quad*4 + reg
    float t_sum = 0.0f, p_exp = 0.0f, p_s = 0.0f;
    int p_cnt = 0;
#pragma unroll
    for (int mt = 0; mt < 2; mt++) {
        int rbase = rowA + wr * 32 + mt * 16 + quad * 4;
        u64 al[4], ah[4]; int ac[4]; float ia[4];
#pragma unroll
        for (int r = 0; r < 4; r++) {
            al[r] = lo[rbase + r]; ah[r] = hi[rbase + r];
            ac[r] = cnt[rbase + r]; ia[r] = invs[rbase + r];
        }
#pragma unroll
        for (int nt = 0; nt < 2; nt++) {
#pragma unroll
            for (int r = 0; r < 4; r++) {
                float s = accf[mt][nt][r] * ia[r] * ib[nt];   // dot * inv_i*inv_j*10
                float es = __expf(s);
                t_sum += es;
                int inter = __popcll(al[r] & jl[nt]) + __popcll(ah[r] & jh[nt]);
                int uni = ac[r] + jc[nt] - inter;
                if ((10 * inter > 3 * uni) && (rbase + r != colg[nt])) {
                    p_exp += es; p_s += s; p_cnt++;
                }
            }
        }
    }

    // per-wave reduction, LDS combine, ONE uncontended store per block
#pragma unroll
    for (int off = 32; off > 0; off >>= 1) {
        t_sum += __shfl_down(t_sum, off);
        p_exp += __shfl_down(p_exp, off);
        p_s   += __shfl_down(p_s, off);
        p_cnt += __shfl_down(p_cnt, off);
    }
    if (lane == 0) { redT[w] = t_sum; redPe[w] = p_exp; redPs[w] = p_s; redC[w] = p_cnt; }
    __syncthreads();
    if (tid == 0) {
        double T = 0, Pe = 0, Ps = 0;
        long long C = 0;
        for (int i = 0; i < 4; i++) {
            T += (double)redT[i]; Pe += (double)redPe[i];
            Ps += (double)redPs[i]; C += redC[i];
        }
        double scale = (bi == bj) ? 1.0 : 2.0;   // symmetry: off-diagonal counts twice
        double* dst = partials + (size_t)blockIdx.x * 8;
        dst[0] = T * scale;
        dst[1] = Pe * scale;
        dst[2] = Ps * scale;
        dst[3] = (double)C * scale;
    }
}

// ---------- finalize: reduce 2080 partials, compute loss ----------
__global__ __launch_bounds__(256) void finalize_kernel(
    const double* __restrict__ partials, float* __restrict__ out) {
    const int tid = threadIdx.x;
    const int lane = tid & 63;
    const int w = tid >> 6;
    double T = 0, Pe = 0, Ps = 0, C = 0;
    for (int i = tid; i < NBLK; i += 256) {
        const double* src = partials + (size_t)i * 8;
        T += src[0]; Pe += src[1]; Ps += src[2]; C += src[3];
    }
#pragma unroll
    for (int off = 32; off > 0; off >>= 1) {
        T += __shfl_down(T, off);
        Pe += __shfl_down(Pe, off);
        Ps += __shfl_down(Ps, off);
        C += __shfl_down(C, off);
    }
    __shared__ double redT[4], redPe[4], redPs[4], redC[4];
    if (lane == 0) { redT[w] = T; redPe[w] = Pe; redPs[w] = Ps; redC[w] = C; }
    __syncthreads();
    if (tid == 0) {
        double Tt = 0, Pet = 0, Pst = 0, n = 0;
        for (int i = 0; i < 4; i++) { Tt += redT[i]; Pet += redPe[i]; Pst += redPs[i]; n += redC[i]; }
        double neg = Tt - Pet;   // negatives incl. diagonal
        double loss = (n > 0.0) ? log(neg) + (Pet / neg - Pst) / n : 0.0;
        out[0] = (float)loss;
    }
}

extern "C" void kernel_launch(void* const* d_in, const int* in_sizes, int n_in,
                              void* d_out, int out_size, void* d_ws, size_t ws_size,
                              hipStream_t stream) {
    const float* rep = (const float*)d_in[0];
    const int* codes = (const int*)d_in[1];
    // d_in[2] = labels, unused by the reference computation

    // workspace layout
    unsigned short* nb = (unsigned short*)d_ws;                // 2 MiB raw bf16
    char* p = (char*)d_ws + (size_t)B_ * D_ * 2;
    float* invs = (float*)p;                                   // 16 KiB
    u64* lo = (u64*)(invs + B_);                               // 32 KiB
    u64* hi = lo + B_;                                         // 32 KiB
    int* cnt = (int*)(hi + B_);                                // 16 KiB
    double* partials = (double*)(cnt + B_);                    // 2080 x 8 doubles = 130 KiB

    float* out = (float*)d_out;

    prep_kernel<<<B_ / 4, 256, 0, stream>>>(rep, codes, nb, invs, lo, hi, cnt);
    fused_kernel<<<NBLK, 256, 0, stream>>>(nb, invs, lo, hi, cnt, partials);
    finalize_kernel<<<1, 256, 0, stream>>>(partials, out);
}